// Round 1
// baseline (493.550 us; speedup 1.0000x reference)
//
#include <hip/hip_runtime.h>
#include <hip/hip_bf16.h>
#include <math.h>

// Problem constants
#define B_ 4
#define S_ 4096
#define H_ 1024
#define I_ 4096
#define M_ (B_*S_)   // 16384 rows
#define N_ I_        // 4096 cols
#define K_ H_        // 1024 reduction

using bf16 = __bf16;
typedef __attribute__((ext_vector_type(4))) __bf16 bf16x4;
typedef __attribute__((ext_vector_type(8))) __bf16 bf16x8;
typedef __attribute__((ext_vector_type(4))) float f32x4;

// ---------------------------------------------------------------
// Kernel 1: fp32 -> bf16 convert of hidden_states (vectorized)
// ---------------------------------------------------------------
__global__ void convert_hidden(const float* __restrict__ x, bf16* __restrict__ y, int n4) {
    int idx = blockIdx.x * blockDim.x + threadIdx.x;
    int stride = gridDim.x * blockDim.x;
    const float4* xv = (const float4*)x;
    bf16x4* yv = (bf16x4*)y;
    for (int i = idx; i < n4; i += stride) {
        float4 v = xv[i];
        bf16x4 o;
        o[0] = (bf16)v.x; o[1] = (bf16)v.y; o[2] = (bf16)v.z; o[3] = (bf16)v.w;
        yv[i] = o;
    }
}

// ---------------------------------------------------------------
// Kernel 2: per-row alpha = mean(|W|) and sign(W) as exact bf16 (+1/-1/0)
// One block (256 threads) per row of W [I_, H_]
// ---------------------------------------------------------------
__global__ void binarize(const float* __restrict__ w, bf16* __restrict__ wb,
                         float* __restrict__ alpha) {
    int row = blockIdx.x;
    int t = threadIdx.x;  // 0..255, each handles 4 elements of H_=1024
    const float4* wr = (const float4*)(w + (size_t)row * H_);
    float4 v = wr[t];
    float s = fabsf(v.x) + fabsf(v.y) + fabsf(v.z) + fabsf(v.w);
    // wave(64) reduce
    #pragma unroll
    for (int off = 32; off; off >>= 1) s += __shfl_down(s, off, 64);
    __shared__ float part[4];
    if ((t & 63) == 0) part[t >> 6] = s;
    __syncthreads();
    float tot = part[0] + part[1] + part[2] + part[3];
    if (t == 0) alpha[row] = tot * (1.0f / H_);
    bf16x4 sg;
    sg[0] = (bf16)((v.x > 0.f) ? 1.f : ((v.x < 0.f) ? -1.f : 0.f));
    sg[1] = (bf16)((v.y > 0.f) ? 1.f : ((v.y < 0.f) ? -1.f : 0.f));
    sg[2] = (bf16)((v.z > 0.f) ? 1.f : ((v.z < 0.f) ? -1.f : 0.f));
    sg[3] = (bf16)((v.w > 0.f) ? 1.f : ((v.w < 0.f) ? -1.f : 0.f));
    ((bf16x4*)(wb + (size_t)row * H_))[t] = sg;
}

// ---------------------------------------------------------------
// Kernel 3: bf16 GEMM (m97 structure) + fused alpha*x + bias + exact GELU
// C[M_,N_] = A[M_,K_] * Wb[N_,K_]^T  (B^T input layout)
// 128x128 tile, BK=32, 4 waves (2x2), each wave 64x64 via 4x4 mfma 16x16x32
// ---------------------------------------------------------------
#define BM 128
#define BN 128
#define BK 32

__device__ __forceinline__ void gload_lds16(const bf16* g, bf16* l) {
    __builtin_amdgcn_global_load_lds(
        (const __attribute__((address_space(1))) void*)g,
        (__attribute__((address_space(3))) void*)l, 16, 0, 0);
}

__global__ __launch_bounds__(256) void gemm_bias_gelu(
    const bf16* __restrict__ A, const bf16* __restrict__ Wb,
    const float* __restrict__ alpha, const float* __restrict__ bias,
    float* __restrict__ out) {
    __shared__ bf16 As[BM * BK];  // 8 KB
    __shared__ bf16 Bs[BN * BK];  // 8 KB

    const int bc = blockIdx.x;   // 0..31  (N tiles)
    const int br = blockIdx.y;   // 0..127 (M tiles)
    const int t = threadIdx.x;   // 0..255
    const int w = t >> 6;        // wave id 0..3
    const int l = t & 63;        // lane
    const int wr = w >> 1;       // wave row 0..1
    const int wc = w & 1;        // wave col 0..1
    const int lrow = l & 15;
    const int lko  = (l >> 4) * 8;  // k offset of this lane's fragment

    f32x4 acc[4][4] = {};

    for (int kt = 0; kt < K_ / BK; ++kt) {
        // --- stage A tile (128x32) and B tile (128x32) via global_load_lds ---
        #pragma unroll
        for (int j = 0; j < 2; ++j) {
            int e = (j * 256 + t) * 8;      // element index in tile
            int r = e >> 5;                 // /BK
            int c = e & 31;                 // %BK
            gload_lds16(A + (size_t)(br * BM + r) * K_ + kt * BK + c, As + e);
        }
        #pragma unroll
        for (int j = 0; j < 2; ++j) {
            int e = (j * 256 + t) * 8;
            int r = e >> 5;
            int c = e & 31;
            gload_lds16(Wb + (size_t)(bc * BN + r) * K_ + kt * BK + c, Bs + e);
        }
        __syncthreads();

        // --- LDS -> fragments, 16 MFMAs ---
        bf16x8 af[4], bfr[4];
        #pragma unroll
        for (int m = 0; m < 4; ++m)
            af[m] = *(const bf16x8*)(As + (wr * 64 + m * 16 + lrow) * BK + lko);
        #pragma unroll
        for (int n = 0; n < 4; ++n)
            bfr[n] = *(const bf16x8*)(Bs + (wc * 64 + n * 16 + lrow) * BK + lko);
        #pragma unroll
        for (int m = 0; m < 4; ++m)
            #pragma unroll
            for (int n = 0; n < 4; ++n)
                acc[m][n] = __builtin_amdgcn_mfma_f32_16x16x32_bf16(
                    af[m], bfr[n], acc[m][n], 0, 0, 0);
        __syncthreads();
    }

    // --- epilogue: alpha * x + bias, exact-erf GELU, fp32 store ---
    const int colb = bc * BN + wc * 64;
    const int rowb = br * BM + wr * 64;
    #pragma unroll
    for (int n = 0; n < 4; ++n) {
        int col = colb + n * 16 + lrow;
        float al = alpha[col];
        float bi = bias[col];
        #pragma unroll
        for (int m = 0; m < 4; ++m) {
            int row0 = rowb + m * 16 + (l >> 4) * 4;
            #pragma unroll
            for (int r = 0; r < 4; ++r) {
                float v = acc[m][n][r] * al + bi;
                float g = 0.5f * v * (1.0f + erff(v * 0.70710678118654752f));
                out[(size_t)(row0 + r) * N_ + col] = g;
            }
        }
    }
}

// ---------------------------------------------------------------
extern "C" void kernel_launch(void* const* d_in, const int* in_sizes, int n_in,
                              void* d_out, int out_size, void* d_ws, size_t ws_size,
                              hipStream_t stream) {
    const float* hidden = (const float*)d_in[0];   // [B,S,H] fp32
    const float* weight = (const float*)d_in[1];   // [I,H]   fp32
    const float* bias   = (const float*)d_in[2];   // [I]     fp32
    float* out = (float*)d_out;                    // [B,S,I] fp32

    // workspace layout
    char* ws = (char*)d_ws;
    bf16* Abf   = (bf16*)ws;                                   // 32 MB
    bf16* Wb    = (bf16*)(ws + (size_t)M_ * K_ * 2);           // 8 MB
    float* alph = (float*)(ws + (size_t)M_ * K_ * 2 + (size_t)N_ * K_ * 2); // 16 KB

    // 1) hidden fp32 -> bf16
    convert_hidden<<<2048, 256, 0, stream>>>(hidden, Abf, (M_ * K_) / 4);
    // 2) binarize weight: alpha + sign(bf16)
    binarize<<<I_, 256, 0, stream>>>(weight, Wb, alph);
    // 3) GEMM + bias + GELU
    dim3 grid(N_ / BN, M_ / BM);
    gemm_bias_gelu<<<grid, 256, 0, stream>>>(Abf, Wb, alph, bias, out);
}

// Round 4
// 458.162 us; speedup vs baseline: 1.0772x; 1.0772x over previous
//
#include <hip/hip_runtime.h>
#include <hip/hip_bf16.h>
#include <math.h>

// Problem constants
#define B_ 4
#define S_ 4096
#define H_ 1024
#define I_ 4096
#define M_ (B_*S_)   // 16384 rows
#define N_ I_        // 4096 cols
#define K_ H_        // 1024 reduction

using bf16 = __bf16;
typedef __attribute__((ext_vector_type(4))) __bf16 bf16x4;
typedef __attribute__((ext_vector_type(8))) __bf16 bf16x8;
typedef __attribute__((ext_vector_type(4))) float f32x4;

// ---------------------------------------------------------------
// Kernel 1: fp32 -> bf16 convert of hidden_states (vectorized)
// ---------------------------------------------------------------
__global__ void convert_hidden(const float* __restrict__ x, bf16* __restrict__ y, int n4) {
    int idx = blockIdx.x * blockDim.x + threadIdx.x;
    int stride = gridDim.x * blockDim.x;
    const float4* xv = (const float4*)x;
    bf16x4* yv = (bf16x4*)y;
    for (int i = idx; i < n4; i += stride) {
        float4 v = xv[i];
        bf16x4 o;
        o[0] = (bf16)v.x; o[1] = (bf16)v.y; o[2] = (bf16)v.z; o[3] = (bf16)v.w;
        yv[i] = o;
    }
}

// ---------------------------------------------------------------
// Kernel 2: per-row alpha = mean(|W|), sign(W) as exact bf16 (+1/-1/0)
// ---------------------------------------------------------------
__global__ void binarize(const float* __restrict__ w, bf16* __restrict__ wb,
                         float* __restrict__ alpha) {
    int row = blockIdx.x;
    int t = threadIdx.x;
    const float4* wr = (const float4*)(w + (size_t)row * H_);
    float4 v = wr[t];
    float s = fabsf(v.x) + fabsf(v.y) + fabsf(v.z) + fabsf(v.w);
    #pragma unroll
    for (int off = 32; off; off >>= 1) s += __shfl_down(s, off, 64);
    __shared__ float part[4];
    if ((t & 63) == 0) part[t >> 6] = s;
    __syncthreads();
    float tot = part[0] + part[1] + part[2] + part[3];
    if (t == 0) alpha[row] = tot * (1.0f / H_);
    bf16x4 sg;
    sg[0] = (bf16)((v.x > 0.f) ? 1.f : ((v.x < 0.f) ? -1.f : 0.f));
    sg[1] = (bf16)((v.y > 0.f) ? 1.f : ((v.y < 0.f) ? -1.f : 0.f));
    sg[2] = (bf16)((v.z > 0.f) ? 1.f : ((v.z < 0.f) ? -1.f : 0.f));
    sg[3] = (bf16)((v.w > 0.f) ? 1.f : ((v.w < 0.f) ? -1.f : 0.f));
    ((bf16x4*)(wb + (size_t)row * H_))[t] = sg;
}

// ---------------------------------------------------------------
// Kernel 3: 256x256 8-phase bf16 GEMM + fused alpha*x + bias + exact GELU
// C[M_,N_] = A[M_,K_] * Wb[N_,K_]^T ; 512 thr = 8 waves (2M x 4N),
// BK=64, LDS = 2 bufs x {A0,A1,B0,B1} halves of 128x64 bf16 (128 KiB).
// Counted vmcnt(8) once per K-tile; XOR bank swizzle on LDS slots.
// ---------------------------------------------------------------
#define BM 256
#define BN 256
#define BK 64
#define NT (K_/BK)   // 16

__device__ __forceinline__ void gload_lds16(const bf16* g, bf16* l) {
    __builtin_amdgcn_global_load_lds(
        (const __attribute__((address_space(1))) void*)g,
        (__attribute__((address_space(3))) void*)l, 16, 0, 0);
}

#define BARRIER() do { __builtin_amdgcn_sched_barrier(0); \
    __builtin_amdgcn_s_barrier(); \
    __builtin_amdgcn_sched_barrier(0); } while (0)
#define LGKM0() do { asm volatile("s_waitcnt lgkmcnt(0)" ::: "memory"); \
    __builtin_amdgcn_sched_barrier(0); } while (0)

__global__ __launch_bounds__(512, 2) void gemm_bias_gelu(
    const bf16* __restrict__ A, const bf16* __restrict__ Wb,
    const float* __restrict__ alpha, const float* __restrict__ bias,
    float* __restrict__ out)
{
    // [buf][region: 0=A half0, 1=A half1, 2=B half0, 3=B half1][128*64]
    __shared__ alignas(16) bf16 sm[2][4][8192];

    // T1: XCD swizzle (nwg=1024 = 8*128). Each XCD owns 2 B-col panels.
    int bid = blockIdx.x;
    int swz = (bid & 7) * 128 + (bid >> 3);
    const int bc = swz >> 6;        // 0..15
    const int br = swz & 63;        // 0..63
    const int brow = br * BM;
    const int bcol = bc * BN;

    const int tid = threadIdx.x;
    const int wid = tid >> 6;
    const int lane = tid & 63;
    const int wr = wid >> 2;   // 0..1 : 64-row band within each 128-row half
    const int wc = wid & 3;    // 0..3 : 32-col band within each 128-col half
    const int q = lane >> 4;   // 0..3
    const int lr = lane & 15;

    // Staging: linear LDS dest, pre-swizzled global source (involution on
    // byte bits [4:6] ^= row&7). off = (j*512+tid)*16 bytes within 16KB half.
    int r_[2], cbE_[2];
    #pragma unroll
    for (int j = 0; j < 2; ++j) {
        int off = (j * 512 + tid) * 16;
        int soff = off ^ (((off >> 7) & 7) << 4);
        r_[j] = soff >> 7;              // row in half (0..127)
        cbE_[j] = (soff & 127) >> 1;    // col offset in bf16 elements
    }
    // Fragment-read swizzled 16B-slot ids (independent of m'/n' since
    // fragment row bases are multiples of 16)
    const int s0 = q ^ (lr & 7);
    const int s1 = (4 + q) ^ (lr & 7);
    const int aRow = wr * 64 + lr;   // row within A half
    const int bRow = wc * 32 + lr;   // row within B half

    f32x4 acc[2][4][2][2] = {}; // [mh][m'][nh][n']

    #define STAGE_A(buf, h, t_) do { _Pragma("unroll") \
        for (int j = 0; j < 2; ++j) \
            gload_lds16(A + (size_t)(brow + (h)*128 + r_[j]) * K_ + (t_)*BK + cbE_[j], \
                        &sm[buf][h][(j*512 + tid) * 8]); } while (0)
    #define STAGE_B(buf, h, t_) do { _Pragma("unroll") \
        for (int j = 0; j < 2; ++j) \
            gload_lds16(Wb + (size_t)(bcol + (h)*128 + r_[j]) * K_ + (t_)*BK + cbE_[j], \
                        &sm[buf][2 + (h)][(j*512 + tid) * 8]); } while (0)

    #define READ_A(buf, mh) do { _Pragma("unroll") \
        for (int m = 0; m < 4; ++m) { \
            aF[m][0] = *(const bf16x8*)&sm[buf][mh][(aRow + m*16) * 64 + s0*8]; \
            aF[m][1] = *(const bf16x8*)&sm[buf][mh][(aRow + m*16) * 64 + s1*8]; \
        } } while (0)
    #define READ_B(dst, buf, nh) do { _Pragma("unroll") \
        for (int n = 0; n < 2; ++n) { \
            dst[n][0] = *(const bf16x8*)&sm[buf][2+(nh)][(bRow + n*16) * 64 + s0*8]; \
            dst[n][1] = *(const bf16x8*)&sm[buf][2+(nh)][(bRow + n*16) * 64 + s1*8]; \
        } } while (0)

    #define MFMA16(MH, NH, bF) do { \
        __builtin_amdgcn_s_setprio(1); \
        _Pragma("unroll") for (int m = 0; m < 4; ++m) \
        _Pragma("unroll") for (int n = 0; n < 2; ++n) \
        _Pragma("unroll") for (int k = 0; k < 2; ++k) \
            acc[MH][m][NH][n] = __builtin_amdgcn_mfma_f32_16x16x32_bf16( \
                aF[m][k], bF[n][k], acc[MH][m][NH][n], 0, 0, 0); \
        __builtin_amdgcn_s_setprio(0); } while (0)

    // Prologue: stage tile0 then tile1 (order A0,B0,B1,A1 matches loop)
    STAGE_A(0, 0, 0); STAGE_B(0, 0, 0); STAGE_B(0, 1, 0); STAGE_A(0, 1, 0);
    STAGE_A(1, 0, 1); STAGE_B(1, 0, 1); STAGE_B(1, 1, 1); STAGE_A(1, 1, 1);

    bf16x8 aF[4][2], bF0[2][2], bF1[2][2];

    for (int t = 0; t < NT; ++t) {
        const int b = t & 1;
        // Tile entry: counted wait (thread's 8 newest loads = tile t+1's),
        // then barrier so ALL waves' shares of tile t are visible.
        if (t == NT - 1) { asm volatile("s_waitcnt vmcnt(0)" ::: "memory"); }
        else             { asm volatile("s_waitcnt vmcnt(8)" ::: "memory"); }
        BARRIER();
        const bool st = (t + 2 < NT);

        // ph0 (mh0,nh0): read A0 + B0; no staging (A0/B0 being read)
        READ_A(b, 0);
        READ_B(bF0, b, 0);
        BARRIER(); LGKM0();
        MFMA16(0, 0, bF0);
        BARRIER();

        // ph1 (mh0,nh1): read B1; stage A0(t+2) (A0 free after ph0)
        READ_B(bF1, b, 1);
        if (st) STAGE_A(b, 0, t + 2);
        BARRIER(); LGKM0();
        MFMA16(0, 1, bF1);
        BARRIER();

        // ph2 (mh1,nh1): read A1; stage B0(t+2) (B0 free after ph0)
        READ_A(b, 1);
        if (st) STAGE_B(b, 0, t + 2);
        BARRIER(); LGKM0();
        MFMA16(1, 1, bF1);
        BARRIER();

        // ph3 (mh1,nh0): bF0 carried in regs; stage B1(t+2), A1(t+2)
        if (st) { STAGE_B(b, 1, t + 2); STAGE_A(b, 1, t + 2); }
        BARRIER(); LGKM0();
        MFMA16(1, 0, bF0);
        // trailing barrier fused into next tile's entry BARRIER
    }

    // ---- epilogue: alpha*x + bias, exact-erf GELU, fp32 stores ----
    float al[2][2], bi[2][2];
    #pragma unroll
    for (int nh = 0; nh < 2; ++nh)
        #pragma unroll
        for (int n = 0; n < 2; ++n) {
            int col = bcol + nh * 128 + wc * 32 + n * 16 + lr;
            al[nh][n] = alpha[col];
            bi[nh][n] = bias[col];
        }
    #pragma unroll
    for (int mh = 0; mh < 2; ++mh)
        #pragma unroll
        for (int m = 0; m < 4; ++m)
            #pragma unroll
            for (int r = 0; r < 4; ++r) {
                size_t row = (size_t)(brow + mh * 128 + wr * 64 + m * 16 + q * 4 + r);
                float* orow = out + row * N_;
                #pragma unroll
                for (int nh = 0; nh < 2; ++nh)
                    #pragma unroll
                    for (int n = 0; n < 2; ++n) {
                        int col = bcol + nh * 128 + wc * 32 + n * 16 + lr;
                        float v = acc[mh][m][nh][n][r] * al[nh][n] + bi[nh][n];
                        float g = 0.5f * v * (1.0f + erff(v * 0.70710678118654752f));
                        orow[col] = g;
                    }
            }
}

// ---------------------------------------------------------------
extern "C" void kernel_launch(void* const* d_in, const int* in_sizes, int n_in,
                              void* d_out, int out_size, void* d_ws, size_t ws_size,
                              hipStream_t stream) {
    const float* hidden = (const float*)d_in[0];   // [B,S,H] fp32
    const float* weight = (const float*)d_in[1];   // [I,H]   fp32
    const float* bias   = (const float*)d_in[2];   // [I]     fp32
    float* out = (float*)d_out;                    // [B,S,I] fp32

    char* ws = (char*)d_ws;
    bf16* Abf   = (bf16*)ws;                                   // 32 MB
    bf16* Wb    = (bf16*)(ws + (size_t)M_ * K_ * 2);           // 8 MB
    float* alph = (float*)(ws + (size_t)M_ * K_ * 2 + (size_t)N_ * K_ * 2);

    convert_hidden<<<2048, 256, 0, stream>>>(hidden, Abf, (M_ * K_) / 4);
    binarize<<<I_, 256, 0, stream>>>(weight, Wb, alph);
    gemm_bias_gelu<<<(M_ / BM) * (N_ / BN), 512, 0, stream>>>(Abf, Wb, alph, bias, out);
}